// Round 14
// baseline (154.448 us; speedup 1.0000x reference)
//
#include <hip/hip_runtime.h>
#include <stdint.h>

#define DGRID 8
#define NVOX  2048      // B * D^3
#define NBATCH 4
#define MMAX  1024
#define FDIM  64
#define CHUNKP 256      // points per sort chunk (fast path)
#define GRP   20        // chunks per scan group

// ---- float <-> order-preserving unsigned encoding ----
__device__ __forceinline__ unsigned encf(float f){
  unsigned u = __float_as_uint(f);
  return (u & 0x80000000u) ? ~u : (u | 0x80000000u);
}
__device__ __forceinline__ float decf(unsigned e){
  unsigned u = (e & 0x80000000u) ? (e ^ 0x80000000u) : ~e;
  return __uint_as_float(u);
}

// ======================= FAST PATH =======================

// F1: per-block partial mins (no atomics); spare blocks zero counts/clustCnt/clustRank
__global__ __launch_bounds__(256) void k_minpart(const float* __restrict__ pos,
    int N, unsigned* __restrict__ bmin, int* __restrict__ counts,
    int* __restrict__ clustCnt, int* __restrict__ clustRank){
  if (blockIdx.x < 8) counts[blockIdx.x * 256 + threadIdx.x] = 0;
  else if (blockIdx.x < 12) clustCnt[(blockIdx.x - 8) * 256 + threadIdx.x] = 0;
  else if (blockIdx.x < 16) clustRank[(blockIdx.x - 12) * 256 + threadIdx.x] = 0;
  unsigned m0 = 0xFFFFFFFFu, m1 = 0xFFFFFFFFu, m2 = 0xFFFFFFFFu;
  int stride = gridDim.x * blockDim.x;
  for (int i = blockIdx.x * blockDim.x + threadIdx.x; i < N; i += stride){
    unsigned e0 = encf(pos[3*i+0]); if (e0 < m0) m0 = e0;
    unsigned e1 = encf(pos[3*i+1]); if (e1 < m1) m1 = e1;
    unsigned e2 = encf(pos[3*i+2]); if (e2 < m2) m2 = e2;
  }
  #pragma unroll
  for (int off = 32; off > 0; off >>= 1){
    unsigned t0 = __shfl_down(m0, off); if (t0 < m0) m0 = t0;
    unsigned t1 = __shfl_down(m1, off); if (t1 < m1) m1 = t1;
    unsigned t2 = __shfl_down(m2, off); if (t2 < m2) m2 = t2;
  }
  __shared__ unsigned sm[4][3];
  int wv = threadIdx.x >> 6, lane = threadIdx.x & 63;
  if (lane == 0){ sm[wv][0] = m0; sm[wv][1] = m1; sm[wv][2] = m2; }
  __syncthreads();
  if (threadIdx.x == 0){
    unsigned a0 = sm[0][0], a1 = sm[0][1], a2 = sm[0][2];
    for (int k = 1; k < 4; k++){
      if (sm[k][0] < a0) a0 = sm[k][0];
      if (sm[k][1] < a1) a1 = sm[k][1];
      if (sm[k][2] < a2) a2 = sm[k][2];
    }
    bmin[blockIdx.x*3+0] = a0;
    bmin[blockIdx.x*3+1] = a1;
    bmin[blockIdx.x*3+2] = a2;
  }
}

// F2: per-chunk voxel histogram (voxel id recomputed later; no vox array).
__global__ __launch_bounds__(256) void k_chist(const float* __restrict__ pos,
    const int* __restrict__ batch, int N, const unsigned* __restrict__ bmin,
    int* __restrict__ chunkHist){
  __shared__ int h[NVOX];
  __shared__ unsigned smin[3];
  for (int t = threadIdx.x; t < NVOX; t += 256) h[t] = 0;
  if (threadIdx.x < 64){
    unsigned a0 = bmin[threadIdx.x*3+0];
    unsigned a1 = bmin[threadIdx.x*3+1];
    unsigned a2 = bmin[threadIdx.x*3+2];
    #pragma unroll
    for (int off = 32; off > 0; off >>= 1){
      unsigned t0 = __shfl_down(a0, off); if (t0 < a0) a0 = t0;
      unsigned t1 = __shfl_down(a1, off); if (t1 < a1) a1 = t1;
      unsigned t2 = __shfl_down(a2, off); if (t2 < a2) a2 = t2;
    }
    if (threadIdx.x == 0){ smin[0] = a0; smin[1] = a1; smin[2] = a2; }
  }
  __syncthreads();
  int c = blockIdx.x;
  int i = c * CHUNKP + threadIdx.x;
  if (i < N){
    float s0 = __fsub_rn(decf(smin[0]), 0.1f);
    float s1 = __fsub_rn(decf(smin[1]), 0.1f);
    float s2 = __fsub_rn(decf(smin[2]), 0.1f);
    float q0 = __fdiv_rn(__fsub_rn(pos[3*i+0], s0), 0.2f);
    float q1 = __fdiv_rn(__fsub_rn(pos[3*i+1], s1), 0.2f);
    float q2 = __fdiv_rn(__fsub_rn(pos[3*i+2], s2), 0.2f);
    int c0 = (int)floorf(q0); c0 = c0 < 0 ? 0 : (c0 > DGRID-1 ? DGRID-1 : c0);
    int c1 = (int)floorf(q1); c1 = c1 < 0 ? 0 : (c1 > DGRID-1 ? DGRID-1 : c1);
    int c2 = (int)floorf(q2); c2 = c2 < 0 ? 0 : (c2 > DGRID-1 ? DGRID-1 : c2);
    int v = ((batch[i]*DGRID + c0)*DGRID + c1)*DGRID + c2;
    atomicAdd(&h[v], 1);
  }
  __syncthreads();
  for (int t = threadIdx.x; t < NVOX; t += 256)
    chunkHist[c * NVOX + t] = h[t];
}

// F3: per-group partial sums over chunks + atomic accumulate into counts
//     (replaces the separate k_gscan dispatch; counts zeroed in k_minpart)
__global__ __launch_bounds__(256) void k_gsum(int nchunks, int ngroups,
    const int* __restrict__ chunkHist, int* __restrict__ gsum,
    int* __restrict__ counts){
  int g = blockIdx.x >> 3;
  int v = (blockIdx.x & 7) * 256 + threadIdx.x;
  if (g >= ngroups) return;
  int c0 = g * GRP, c1 = min(nchunks, c0 + GRP);
  int s = 0;
  for (int c = c0; c < c1; c++) s += chunkHist[c * NVOX + v];
  gsum[g * NVOX + v] = s;
  if (s > 0) atomicAdd(&counts[v], s);
}

// F4: stable scatter + FUSED compaction scan (wave 0 redundant per block;
//     block 0 writes Mout/batchStartC/idxOfCluster/voxBase) + self-computed
//     group prefix (raw gsum rows g'<g) + recomputed voxel ids (no vox array).
__global__ __launch_bounds__(256) void k_scatter(const float* __restrict__ pos,
    const int* __restrict__ batch, int N, const int* __restrict__ chunkHist,
    const int* __restrict__ gsum, const int* __restrict__ counts,
    const unsigned* __restrict__ bmin,
    int* Mout, int* batchStartC, int* __restrict__ idxOfCluster,
    int* __restrict__ voxBaseG, float* __restrict__ pos_sorted){
  __shared__ int sBase[NVOX];         // 8 KB: voxBase, then chunk base
  __shared__ int rowCnt[4][NVOX];     // 32 KB
  __shared__ unsigned smin[3];
  int c = blockIdx.x;
  int wv = threadIdx.x >> 6, lane = threadIdx.x & 63;
  if (wv == 0){
    // redundant single-wave compaction/base scan from counts
    int cs[32];
    int ne = 0, tot = 0;
    #pragma unroll
    for (int j = 0; j < 32; j++){
      int cc2 = counts[lane*32 + j];
      cs[j] = cc2; ne += (cc2 > 0) ? 1 : 0; tot += cc2;
    }
    int inc = ne, incT = tot;
    #pragma unroll
    for (int off = 1; off < 64; off <<= 1){
      int t  = __shfl_up(inc,  off);
      int tt = __shfl_up(incT, off);
      if (lane >= off){ inc += t; incT += tt; }
    }
    int exne = inc - ne, exT = incT - tot;
    int run = exne, bb = exT;
    #pragma unroll
    for (int j = 0; j < 32; j++){
      sBase[lane*32 + j] = bb;
      if (c == 0) voxBaseG[lane*32 + j] = bb;
      bb += cs[j];
      if (cs[j] > 0){
        if (c == 0 && run < MMAX) idxOfCluster[run] = lane*32 + j;
        run++;
      }
    }
    if (c == 0){
      int M = __shfl(run, 63);
      for (int m = M + lane; m < MMAX; m += 64) idxOfCluster[m] = 0;
      int ex0  = __shfl(exne, 0),  ex16 = __shfl(exne, 16);
      int ex32 = __shfl(exne, 32), ex48 = __shfl(exne, 48);
      if (lane == 0){
        Mout[0] = M;
        batchStartC[0] = ex0;  batchStartC[1] = ex16;
        batchStartC[2] = ex32; batchStartC[3] = ex48;
        batchStartC[NBATCH] = (M < MMAX) ? M : MMAX;
      }
    }
  } else {
    if (wv == 1){
      unsigned a0 = bmin[lane*3+0];
      unsigned a1 = bmin[lane*3+1];
      unsigned a2 = bmin[lane*3+2];
      #pragma unroll
      for (int off = 32; off > 0; off >>= 1){
        unsigned t0 = __shfl_down(a0, off); if (t0 < a0) a0 = t0;
        unsigned t1 = __shfl_down(a1, off); if (t1 < a1) a1 = t1;
        unsigned t2 = __shfl_down(a2, off); if (t2 < a2) a2 = t2;
      }
      if (lane == 0){ smin[0] = a0; smin[1] = a1; smin[2] = a2; }
    }
    for (int t = threadIdx.x - 64; t < 4*NVOX; t += 192)
      ((int*)rowCnt)[t] = 0;
  }
  __syncthreads();
  {
    int g = c / GRP, cg0 = g * GRP;
    for (int t = threadIdx.x; t < NVOX; t += 256){
      int b = sBase[t];
      for (int gg = 0; gg < g; gg++) b += gsum[gg * NVOX + t];
      for (int cc = cg0; cc < c; cc++) b += chunkHist[cc * NVOX + t];
      sBase[t] = b;
    }
  }
  __syncthreads();
  int i = c * CHUNKP + threadIdx.x;
  bool valid = i < N;
  int v = -1;
  float px = 0.f, py = 0.f, pz = 0.f;
  if (valid){
    px = pos[3*i+0]; py = pos[3*i+1]; pz = pos[3*i+2];
    float s0 = __fsub_rn(decf(smin[0]), 0.1f);
    float s1 = __fsub_rn(decf(smin[1]), 0.1f);
    float s2 = __fsub_rn(decf(smin[2]), 0.1f);
    float q0 = __fdiv_rn(__fsub_rn(px, s0), 0.2f);
    float q1 = __fdiv_rn(__fsub_rn(py, s1), 0.2f);
    float q2 = __fdiv_rn(__fsub_rn(pz, s2), 0.2f);
    int c0 = (int)floorf(q0); c0 = c0 < 0 ? 0 : (c0 > DGRID-1 ? DGRID-1 : c0);
    int c1 = (int)floorf(q1); c1 = c1 < 0 ? 0 : (c1 > DGRID-1 ? DGRID-1 : c1);
    int c2 = (int)floorf(q2); c2 = c2 < 0 ? 0 : (c2 > DGRID-1 ? DGRID-1 : c2);
    v = ((batch[i]*DGRID + c0)*DGRID + c1)*DGRID + c2;
  }
  int rank = 0, cnt = 0;
  #pragma unroll 8
  for (int j = 0; j < 64; j++){
    int vj = __shfl(v, j);
    if (vj == v){
      cnt++;
      if (j < lane) rank++;
    }
  }
  if (valid && rank == 0) rowCnt[wv][v] = cnt;
  __syncthreads();
  if (valid){
    int pre = 0;
    for (int rr = 0; rr < wv; rr++) pre += rowCnt[rr][v];
    int dst = sBase[v] + pre + rank;
    pos_sorted[3*dst+0] = px;
    pos_sorted[3*dst+1] = py;
    pos_sorted[3*dst+2] = pz;
  }
}

// F5: per-voxel fp32 sums (bitwise-sequential __fadd_rn chain) + centroid + c2
__global__ __launch_bounds__(64) void k_sum2cent(const float* __restrict__ pos_sorted,
    const int* __restrict__ voxBase, const int* __restrict__ counts,
    float4* __restrict__ centv){
  int v = blockIdx.x * 64 + threadIdx.x;
  if (v >= NVOX) return;
  int lo = voxBase[v], cnt = counts[v];
  const float* p = pos_sorted + 3*(size_t)lo;
  float sx = 0.f, sy = 0.f, sz = 0.f;
  int k = 0;
  for (; k + 4 <= cnt; k += 4){
    float a0 = p[0],  a1 = p[1],  a2 = p[2];
    float b0 = p[3],  b1 = p[4],  b2 = p[5];
    float c0 = p[6],  c1 = p[7],  c2 = p[8];
    float d0 = p[9],  d1 = p[10], d2 = p[11];
    sx = __fadd_rn(__fadd_rn(__fadd_rn(__fadd_rn(sx, a0), b0), c0), d0);
    sy = __fadd_rn(__fadd_rn(__fadd_rn(__fadd_rn(sy, a1), b1), c1), d1);
    sz = __fadd_rn(__fadd_rn(__fadd_rn(__fadd_rn(sz, a2), b2), c2), d2);
    p += 12;
  }
  for (; k < cnt; k++){
    sx = __fadd_rn(sx, p[0]);
    sy = __fadd_rn(sy, p[1]);
    sz = __fadd_rn(sz, p[2]);
    p += 3;
  }
  float den = fmaxf((float)cnt, 1.0f);
  float cx = __fdiv_rn(sx, den);
  float cy = __fdiv_rn(sy, den);
  float cz = __fdiv_rn(sz, den);
  float c2 = __fadd_rn(__fadd_rn(__fmul_rn(cx,cx), __fmul_rn(cy,cy)), __fmul_rn(cz,cz));
  centv[v] = make_float4(cx, cy, cz, c2);
}

// F6: per-point argmin (EXACT fp32 code) with gathered centroid table;
//     block 0 writes outC/outNB/outValid; fused LDS cluster hist -> clustCnt.
__global__ __launch_bounds__(256) void k_argmin2(const float* __restrict__ pos,
    const int* __restrict__ batch, int N, const float4* __restrict__ centv,
    const int* __restrict__ idxOfCluster, const int* __restrict__ Mout,
    const int* __restrict__ batchStartC, int* __restrict__ assign,
    int* __restrict__ clustCnt, float* __restrict__ outC,
    float* __restrict__ outNB, float* __restrict__ outValid){
  __shared__ float4 sc[MMAX];         // 16 KB
  __shared__ int h[MMAX];             // 4 KB
  for (int m = threadIdx.x; m < MMAX; m += 256){
    sc[m] = centv[idxOfCluster[m]];
    h[m] = 0;
  }
  __syncthreads();
  if (blockIdx.x == 0){
    int M = Mout[0];
    for (int m = threadIdx.x; m < MMAX; m += 256){
      float4 cc = sc[m];
      outC[3*m+0] = cc.x; outC[3*m+1] = cc.y; outC[3*m+2] = cc.z;
      outNB[m] = (float)(idxOfCluster[m] >> 9);
      outValid[m] = (m < M) ? 1.0f : 0.0f;
    }
  }
  int i = blockIdx.x * 256 + threadIdx.x;
  if (i < N){
    float px = pos[3*i+0], py = pos[3*i+1], pz = pos[3*i+2];
    float p2 = __fadd_rn(__fadd_rn(__fmul_rn(px,px), __fmul_rn(py,py)), __fmul_rn(pz,pz));
    int b = batch[i];
    int mlo = batchStartC[b], mhi = batchStartC[b+1];
    float best = 3.402823466e+38f;
    int bm = mlo;
    for (int m = mlo; m < mhi; m++){
      float4 cc = sc[m];
      float dot = __fadd_rn(__fadd_rn(__fmul_rn(px,cc.x), __fmul_rn(py,cc.y)),
                            __fmul_rn(pz,cc.z));
      float d2  = __fadd_rn(__fsub_rn(p2, __fmul_rn(2.0f, dot)), cc.w);
      if (d2 < best){ best = d2; bm = m; }
    }
    assign[i] = bm;
    atomicAdd(&h[bm], 1);
  }
  __syncthreads();
  for (int t = threadIdx.x; t < MMAX; t += 256){
    int c = h[t];
    if (c > 0) atomicAdd(&clustCnt[t], c);
  }
}

// F7: index scatter by cluster + FUSED redundant cluster-base scan (wave 0;
//     block 0 writes clustBaseG). Rank via global clustRank atomics
//     (zeroed in k_minpart). fmax is order-independent -> unordered ok.
__global__ __launch_bounds__(256) void k_scatter2s(const int* __restrict__ assign,
    int N, const int* __restrict__ clustCnt, int* __restrict__ clustRank,
    int* __restrict__ clustBaseG, int* __restrict__ idx_sorted){
  __shared__ int cb[MMAX];            // 4 KB
  int wv = threadIdx.x >> 6, lane = threadIdx.x & 63;
  if (wv == 0){
    int cs[16]; int tot = 0;
    #pragma unroll
    for (int j = 0; j < 16; j++){ cs[j] = clustCnt[lane*16 + j]; tot += cs[j]; }
    int inc = tot;
    #pragma unroll
    for (int off = 1; off < 64; off <<= 1){
      int t = __shfl_up(inc, off);
      if (lane >= off) inc += t;
    }
    int bb = inc - tot;
    #pragma unroll
    for (int j = 0; j < 16; j++){
      cb[lane*16 + j] = bb;
      if (blockIdx.x == 0) clustBaseG[lane*16 + j] = bb;
      bb += cs[j];
    }
  }
  __syncthreads();
  int i = blockIdx.x * 256 + threadIdx.x;
  if (i >= N) return;
  int m = assign[i];
  int r = atomicAdd(&clustRank[m], 1);
  idx_sorted[cb[m] + r] = i;
}

// F8: per-cluster feature max. One wave per cluster, lane = feature.
__global__ __launch_bounds__(256) void k_xmax(const float* __restrict__ x,
    const int* __restrict__ idx_sorted, const int* __restrict__ clustBase,
    const int* __restrict__ clustCnt, float* __restrict__ outX){
  int w = blockIdx.x * 4 + (threadIdx.x >> 6);
  int lane = threadIdx.x & 63;
  if (w >= MMAX) return;
  int lo = clustBase[w], cnt = clustCnt[w];
  float mx = -3.402823466e+38f;
  int k = 0;
  for (; k + 4 <= cnt; k += 4){
    int r0 = idx_sorted[lo+k+0], r1 = idx_sorted[lo+k+1];
    int r2 = idx_sorted[lo+k+2], r3 = idx_sorted[lo+k+3];
    float a = x[(size_t)r0 * FDIM + lane];
    float b = x[(size_t)r1 * FDIM + lane];
    float c = x[(size_t)r2 * FDIM + lane];
    float d = x[(size_t)r3 * FDIM + lane];
    mx = fmaxf(mx, fmaxf(fmaxf(a, b), fmaxf(c, d)));
  }
  for (; k < cnt; k++){
    int r0 = idx_sorted[lo+k];
    mx = fmaxf(mx, x[(size_t)r0 * FDIM + lane]);
  }
  outX[w * FDIM + lane] = (cnt > 0) ? mx : 0.0f;
}

// ======================= SLOW-PATH FALLBACK (ws too small) =======================

__global__ __launch_bounds__(256) void k_init(unsigned* startEnc, int* batchCnt){
  int t = threadIdx.x;
  if (t < 3) startEnc[t] = 0xFFFFFFFFu;
  if (t < NBATCH) batchCnt[t] = 0;
}

__global__ __launch_bounds__(256) void k_min_hist(const float* __restrict__ pos,
    const int* __restrict__ batch, int N, unsigned* startEnc, int* batchCnt){
  __shared__ int sbin[NBATCH];
  if (threadIdx.x < NBATCH) sbin[threadIdx.x] = 0;
  __syncthreads();
  unsigned m0 = 0xFFFFFFFFu, m1 = 0xFFFFFFFFu, m2 = 0xFFFFFFFFu;
  int stride = gridDim.x * blockDim.x;
  for (int i = blockIdx.x * blockDim.x + threadIdx.x; i < N; i += stride){
    unsigned e0 = encf(pos[3*i+0]); if (e0 < m0) m0 = e0;
    unsigned e1 = encf(pos[3*i+1]); if (e1 < m1) m1 = e1;
    unsigned e2 = encf(pos[3*i+2]); if (e2 < m2) m2 = e2;
    atomicAdd(&sbin[batch[i]], 1);
  }
  #pragma unroll
  for (int off = 32; off > 0; off >>= 1){
    unsigned t0 = __shfl_down(m0, off); if (t0 < m0) m0 = t0;
    unsigned t1 = __shfl_down(m1, off); if (t1 < m1) m1 = t1;
    unsigned t2 = __shfl_down(m2, off); if (t2 < m2) m2 = t2;
  }
  if ((threadIdx.x & 63) == 0){
    atomicMin(&startEnc[0], m0);
    atomicMin(&startEnc[1], m1);
    atomicMin(&startEnc[2], m2);
  }
  __syncthreads();
  if (threadIdx.x < NBATCH) atomicAdd(&batchCnt[threadIdx.x], sbin[threadIdx.x]);
}

__global__ __launch_bounds__(256) void k_vox(const float* __restrict__ pos,
    const int* __restrict__ batch, int N, const unsigned* __restrict__ startEnc,
    int* __restrict__ vox, int* __restrict__ counts){
  int i = blockIdx.x * blockDim.x + threadIdx.x;
  if (i >= N) return;
  float s0 = __fsub_rn(decf(startEnc[0]), 0.1f);
  float s1 = __fsub_rn(decf(startEnc[1]), 0.1f);
  float s2 = __fsub_rn(decf(startEnc[2]), 0.1f);
  float q0 = __fdiv_rn(__fsub_rn(pos[3*i+0], s0), 0.2f);
  float q1 = __fdiv_rn(__fsub_rn(pos[3*i+1], s1), 0.2f);
  float q2 = __fdiv_rn(__fsub_rn(pos[3*i+2], s2), 0.2f);
  int c0 = (int)floorf(q0); c0 = c0 < 0 ? 0 : (c0 > DGRID-1 ? DGRID-1 : c0);
  int c1 = (int)floorf(q1); c1 = c1 < 0 ? 0 : (c1 > DGRID-1 ? DGRID-1 : c1);
  int c2 = (int)floorf(q2); c2 = c2 < 0 ? 0 : (c2 > DGRID-1 ? DGRID-1 : c2);
  int v = ((batch[i]*DGRID + c0)*DGRID + c1)*DGRID + c2;
  vox[i] = v;
  atomicAdd(&counts[v], 1);
}

__global__ __launch_bounds__(64) void k_scan_old(const int* __restrict__ counts,
    const int* __restrict__ batchCnt, int* batchPtr, int* Mout,
    int* batchStartC, int* __restrict__ idxOfCluster, int* __restrict__ voxBase){
  int lane = threadIdx.x;
  int cs[32];
  int ne = 0, tot = 0;
  #pragma unroll
  for (int j = 0; j < 32; j++){
    int c = counts[lane*32 + j];
    cs[j] = c;
    ne += (c > 0) ? 1 : 0;
    tot += c;
  }
  int inc = ne, incT = tot;
  #pragma unroll
  for (int off = 1; off < 64; off <<= 1){
    int t  = __shfl_up(inc,  off);
    int tt = __shfl_up(incT, off);
    if (lane >= off){ inc += t; incT += tt; }
  }
  int exne = inc - ne;
  int bb   = incT - tot;
  int run = exne;
  #pragma unroll
  for (int j = 0; j < 32; j++){
    voxBase[lane*32 + j] = bb;
    bb += cs[j];
    if (cs[j] > 0){
      if (run < MMAX) idxOfCluster[run] = lane*32 + j;
      run++;
    }
  }
  int M = __shfl(run, 63);
  for (int m = M + lane; m < MMAX; m += 64) idxOfCluster[m] = 0;
  int ex0  = __shfl(exne, 0);
  int ex16 = __shfl(exne, 16);
  int ex32 = __shfl(exne, 32);
  int ex48 = __shfl(exne, 48);
  if (lane == 0){
    Mout[0] = M;
    int acc = 0;
    for (int b = 0; b < NBATCH; b++){ batchPtr[b] = acc; acc += batchCnt[b]; }
    batchPtr[NBATCH] = acc;
    batchStartC[0] = ex0;  batchStartC[1] = ex16;
    batchStartC[2] = ex32; batchStartC[3] = ex48;
    batchStartC[NBATCH] = (M < MMAX) ? M : MMAX;
  }
}

__global__ __launch_bounds__(64) void k_sum(const float* __restrict__ pos,
    const int* __restrict__ vox, const int* __restrict__ counts,
    const int* __restrict__ batchPtr, float* __restrict__ sum_pos){
  int v = blockIdx.x * 64 + threadIdx.x;
  if (v >= NVOX) return;
  int b = v >> 9;
  int lo = batchPtr[b], hi = batchPtr[b+1];
  float sx = 0.f, sy = 0.f, sz = 0.f;
  if (counts[v] > 0){
    for (int i = lo; i < hi; i++){
      if (vox[i] == v){
        sx = __fadd_rn(sx, pos[3*i+0]);
        sy = __fadd_rn(sy, pos[3*i+1]);
        sz = __fadd_rn(sz, pos[3*i+2]);
      }
    }
  }
  sum_pos[3*v+0] = sx;
  sum_pos[3*v+1] = sy;
  sum_pos[3*v+2] = sz;
}

__global__ __launch_bounds__(256) void k_cent(const float* __restrict__ sum_pos,
    const int* __restrict__ counts, const int* __restrict__ idxOfCluster,
    const int* __restrict__ Mout, float4* __restrict__ cent4,
    float* __restrict__ outC, float* __restrict__ outNB, float* __restrict__ outValid){
  int m = blockIdx.x * blockDim.x + threadIdx.x;
  if (m >= MMAX) return;
  int M = Mout[0];
  int v = idxOfCluster[m];
  float den = fmaxf((float)counts[v], 1.0f);
  float cx = __fdiv_rn(sum_pos[3*v+0], den);
  float cy = __fdiv_rn(sum_pos[3*v+1], den);
  float cz = __fdiv_rn(sum_pos[3*v+2], den);
  float c2 = __fadd_rn(__fadd_rn(__fmul_rn(cx,cx), __fmul_rn(cy,cy)), __fmul_rn(cz,cz));
  cent4[m] = make_float4(cx, cy, cz, c2);
  outC[3*m+0] = cx; outC[3*m+1] = cy; outC[3*m+2] = cz;
  outNB[m] = (float)(v >> 9);
  outValid[m] = (m < M) ? 1.0f : 0.0f;
}

__global__ __launch_bounds__(256) void k_assign_slow(const float* __restrict__ pos,
    const float* __restrict__ x, const int* __restrict__ batch, int N,
    const float4* __restrict__ cent4, const int* __restrict__ batchStartC,
    unsigned* __restrict__ encMax){
  __shared__ float4 sc[MMAX];
  for (int m = threadIdx.x; m < MMAX; m += blockDim.x) sc[m] = cent4[m];
  __syncthreads();
  int i = blockIdx.x * blockDim.x + threadIdx.x;
  if (i >= N) return;
  float px = pos[3*i+0], py = pos[3*i+1], pz = pos[3*i+2];
  float p2 = __fadd_rn(__fadd_rn(__fmul_rn(px,px), __fmul_rn(py,py)), __fmul_rn(pz,pz));
  int b = batch[i];
  int mlo = batchStartC[b], mhi = batchStartC[b+1];
  float best = 3.402823466e+38f;
  int bm = mlo;
  for (int m = mlo; m < mhi; m++){
    float4 c = sc[m];
    float dot = __fadd_rn(__fadd_rn(__fmul_rn(px,c.x), __fmul_rn(py,c.y)),
                          __fmul_rn(pz,c.z));
    float d2  = __fadd_rn(__fsub_rn(p2, __fmul_rn(2.0f, dot)), c.w);
    if (d2 < best){ best = d2; bm = m; }
  }
  unsigned* dst = encMax + bm * FDIM;
  const float4* xi = (const float4*)(x + (size_t)i * FDIM);
  #pragma unroll
  for (int f4 = 0; f4 < FDIM/4; f4++){
    float4 xv = xi[f4];
    atomicMax(&dst[4*f4+0], encf(xv.x));
    atomicMax(&dst[4*f4+1], encf(xv.y));
    atomicMax(&dst[4*f4+2], encf(xv.z));
    atomicMax(&dst[4*f4+3], encf(xv.w));
  }
}
__global__ __launch_bounds__(256) void k_decode(const unsigned* __restrict__ encMax,
    float* __restrict__ outX){
  int t = blockIdx.x * blockDim.x + threadIdx.x;
  if (t >= MMAX * FDIM) return;
  unsigned e = encMax[t];
  outX[t] = (e == 0u) ? 0.0f : decf(e);
}

// ---- workspace layout (bytes) ----
// 0      : bmin          64 x 3 x u32 (768)
// 768    : startEnc      12   (slow)
// 784    : batchCnt      16   (slow)
// 800    : batchPtr      20   (slow)
// 832    : Mout          4
// 848    : batchStartC   20
// 896    : counts        8192
// 9088   : voxBase(G)    8192
// 17280  : sum_pos       24576 (slow)
// 41856  : idxOfCluster  4096
// 45952  : cent4         16384 (slow)
// 62336  : clustCnt      4096
// 66432  : clustBase(G)  4096
// 70528  : clustRank     4096  (slow: "cur")
// 74624  : centv         2048 x float4 (32768)
// 107392 : encMax 256KB (slow) / gsum ngroups x 2048 x i32 (fast, <=256KB)
// 369536 : vox           N x i32 (slow path only)
// then   : chunkHist     nchunks x 2048 x i32
// then   : pos_sorted    N x 3 x f32  [alias after k_sum2cent: assign(N) | idx_sorted(N)]

extern "C" void kernel_launch(void* const* d_in, const int* in_sizes, int n_in,
                              void* d_out, int out_size, void* d_ws, size_t ws_size,
                              hipStream_t stream){
  const float* pos   = (const float*)d_in[0];
  const float* x     = (const float*)d_in[1];
  const int*   batch = (const int*)d_in[2];
  const int N = in_sizes[2];

  char* w = (char*)d_ws;
  unsigned* bmin         = (unsigned*)(w + 0);
  unsigned* startEnc     = (unsigned*)(w + 768);
  int*      batchCnt     = (int*)(w + 784);
  int*      batchPtr     = (int*)(w + 800);
  int*      Mout         = (int*)(w + 832);
  int*      batchStartC  = (int*)(w + 848);
  int*      counts       = (int*)(w + 896);
  int*      voxBaseG     = (int*)(w + 9088);
  float*    sum_pos      = (float*)(w + 17280);
  int*      idxOfCluster = (int*)(w + 41856);
  float4*   cent4        = (float4*)(w + 45952);
  int*      clustCnt     = (int*)(w + 62336);
  int*      clustBaseG   = (int*)(w + 66432);
  int*      clustRank    = (int*)(w + 70528);
  float4*   centv        = (float4*)(w + 74624);
  unsigned* encMax       = (unsigned*)(w + 107392);
  int*      gsum         = (int*)(w + 107392);   // fast-path alias
  int*      vox          = (int*)(w + 369536);
  size_t voxEnd = 369536 + (size_t)N * 4;
  size_t chOff  = (voxEnd + 15) & ~(size_t)15;

  int nchunks = (N + CHUNKP - 1) / CHUNKP;
  int ngroups = (nchunks + GRP - 1) / GRP;
  size_t psOff = chOff + (size_t)nchunks * NVOX * 4;
  size_t need  = psOff + (size_t)N * 3 * 4;
  const bool fast = (ws_size >= need) && (ngroups <= 32);

  int*   chunkHist  = (int*)(w + chOff);
  float* pos_sorted = (float*)(w + psOff);
  int* assign     = (int*)pos_sorted;         // after k_sum2cent
  int* idx_sorted = (int*)pos_sorted + N;

  float* outX     = (float*)d_out;          // [1024,64]
  float* outC     = outX + MMAX * FDIM;     // [1024,3]
  float* outNB    = outC + MMAX * 3;        // [1024]
  float* outValid = outNB + MMAX;           // [1024]

  const int nb = (N + 255) / 256;
  if (fast){
    k_minpart<<<64, 256, 0, stream>>>(pos, N, bmin, counts, clustCnt, clustRank);
    k_chist<<<nchunks, 256, 0, stream>>>(pos, batch, N, bmin, chunkHist);
    k_gsum<<<ngroups * 8, 256, 0, stream>>>(nchunks, ngroups, chunkHist, gsum, counts);
    k_scatter<<<nchunks, 256, 0, stream>>>(pos, batch, N, chunkHist, gsum, counts,
                                           bmin, Mout, batchStartC, idxOfCluster,
                                           voxBaseG, pos_sorted);
    k_sum2cent<<<NVOX / 64, 64, 0, stream>>>(pos_sorted, voxBaseG, counts, centv);
    k_argmin2<<<nb, 256, 0, stream>>>(pos, batch, N, centv, idxOfCluster, Mout,
                                      batchStartC, assign, clustCnt,
                                      outC, outNB, outValid);
    k_scatter2s<<<nb, 256, 0, stream>>>(assign, N, clustCnt, clustRank,
                                        clustBaseG, idx_sorted);
    k_xmax<<<MMAX / 4, 256, 0, stream>>>(x, idx_sorted, clustBaseG, clustCnt, outX);
  } else {
    k_init<<<1, 256, 0, stream>>>(startEnc, batchCnt);
    hipMemsetAsync(counts, 0, NVOX * 4, stream);
    hipMemsetAsync(encMax, 0, MMAX * FDIM * 4, stream);
    k_min_hist<<<256, 256, 0, stream>>>(pos, batch, N, startEnc, batchCnt);
    k_vox<<<nb, 256, 0, stream>>>(pos, batch, N, startEnc, vox, counts);
    k_scan_old<<<1, 64, 0, stream>>>(counts, batchCnt, batchPtr, Mout, batchStartC,
                                     idxOfCluster, voxBaseG);
    k_sum<<<(NVOX + 63) / 64, 64, 0, stream>>>(pos, vox, counts, batchPtr, sum_pos);
    k_cent<<<MMAX / 256, 256, 0, stream>>>(sum_pos, counts, idxOfCluster, Mout,
                                           cent4, outC, outNB, outValid);
    k_assign_slow<<<nb, 256, 0, stream>>>(pos, x, batch, N, cent4, batchStartC, encMax);
    k_decode<<<(MMAX * FDIM + 255) / 256, 256, 0, stream>>>(encMax, outX);
  }
}

// Round 15
// 149.393 us; speedup vs baseline: 1.0338x; 1.0338x over previous
//
#include <hip/hip_runtime.h>
#include <stdint.h>

#define DGRID 8
#define NVOX  2048      // B * D^3
#define NBATCH 4
#define MMAX  1024
#define FDIM  64
#define CHUNKP 256      // points per sort chunk (fast path)
#define GRP   20        // chunks per scan group

// ---- float <-> order-preserving unsigned encoding ----
__device__ __forceinline__ unsigned encf(float f){
  unsigned u = __float_as_uint(f);
  return (u & 0x80000000u) ? ~u : (u | 0x80000000u);
}
__device__ __forceinline__ float decf(unsigned e){
  unsigned u = (e & 0x80000000u) ? (e ^ 0x80000000u) : ~e;
  return __uint_as_float(u);
}

// ======================= FAST PATH =======================

// F1: per-block partial mins (no atomics); spare blocks zero counts/clustCnt/clustRank
__global__ __launch_bounds__(256) void k_minpart(const float* __restrict__ pos,
    int N, unsigned* __restrict__ bmin, int* __restrict__ counts,
    int* __restrict__ clustCnt, int* __restrict__ clustRank){
  if (blockIdx.x < 8) counts[blockIdx.x * 256 + threadIdx.x] = 0;
  else if (blockIdx.x < 12) clustCnt[(blockIdx.x - 8) * 256 + threadIdx.x] = 0;
  else if (blockIdx.x < 16) clustRank[(blockIdx.x - 12) * 256 + threadIdx.x] = 0;
  unsigned m0 = 0xFFFFFFFFu, m1 = 0xFFFFFFFFu, m2 = 0xFFFFFFFFu;
  int stride = gridDim.x * blockDim.x;
  for (int i = blockIdx.x * blockDim.x + threadIdx.x; i < N; i += stride){
    unsigned e0 = encf(pos[3*i+0]); if (e0 < m0) m0 = e0;
    unsigned e1 = encf(pos[3*i+1]); if (e1 < m1) m1 = e1;
    unsigned e2 = encf(pos[3*i+2]); if (e2 < m2) m2 = e2;
  }
  #pragma unroll
  for (int off = 32; off > 0; off >>= 1){
    unsigned t0 = __shfl_down(m0, off); if (t0 < m0) m0 = t0;
    unsigned t1 = __shfl_down(m1, off); if (t1 < m1) m1 = t1;
    unsigned t2 = __shfl_down(m2, off); if (t2 < m2) m2 = t2;
  }
  __shared__ unsigned sm[4][3];
  int wv = threadIdx.x >> 6, lane = threadIdx.x & 63;
  if (lane == 0){ sm[wv][0] = m0; sm[wv][1] = m1; sm[wv][2] = m2; }
  __syncthreads();
  if (threadIdx.x == 0){
    unsigned a0 = sm[0][0], a1 = sm[0][1], a2 = sm[0][2];
    for (int k = 1; k < 4; k++){
      if (sm[k][0] < a0) a0 = sm[k][0];
      if (sm[k][1] < a1) a1 = sm[k][1];
      if (sm[k][2] < a2) a2 = sm[k][2];
    }
    bmin[blockIdx.x*3+0] = a0;
    bmin[blockIdx.x*3+1] = a1;
    bmin[blockIdx.x*3+2] = a2;
  }
}

// F2: voxel id per point + per-chunk LDS histogram; block-local min reduction
__global__ __launch_bounds__(256) void k_vox_hist(const float* __restrict__ pos,
    const int* __restrict__ batch, int N, const unsigned* __restrict__ bmin,
    int* __restrict__ vox, int* __restrict__ chunkHist){
  __shared__ int h[NVOX];
  __shared__ unsigned smin[3];
  for (int t = threadIdx.x; t < NVOX; t += 256) h[t] = 0;
  if (threadIdx.x < 64){
    unsigned a0 = bmin[threadIdx.x*3+0];
    unsigned a1 = bmin[threadIdx.x*3+1];
    unsigned a2 = bmin[threadIdx.x*3+2];
    #pragma unroll
    for (int off = 32; off > 0; off >>= 1){
      unsigned t0 = __shfl_down(a0, off); if (t0 < a0) a0 = t0;
      unsigned t1 = __shfl_down(a1, off); if (t1 < a1) a1 = t1;
      unsigned t2 = __shfl_down(a2, off); if (t2 < a2) a2 = t2;
    }
    if (threadIdx.x == 0){ smin[0] = a0; smin[1] = a1; smin[2] = a2; }
  }
  __syncthreads();
  int c = blockIdx.x;
  int i = c * CHUNKP + threadIdx.x;
  if (i < N){
    float s0 = __fsub_rn(decf(smin[0]), 0.1f);
    float s1 = __fsub_rn(decf(smin[1]), 0.1f);
    float s2 = __fsub_rn(decf(smin[2]), 0.1f);
    float q0 = __fdiv_rn(__fsub_rn(pos[3*i+0], s0), 0.2f);
    float q1 = __fdiv_rn(__fsub_rn(pos[3*i+1], s1), 0.2f);
    float q2 = __fdiv_rn(__fsub_rn(pos[3*i+2], s2), 0.2f);
    int c0 = (int)floorf(q0); c0 = c0 < 0 ? 0 : (c0 > DGRID-1 ? DGRID-1 : c0);
    int c1 = (int)floorf(q1); c1 = c1 < 0 ? 0 : (c1 > DGRID-1 ? DGRID-1 : c1);
    int c2 = (int)floorf(q2); c2 = c2 < 0 ? 0 : (c2 > DGRID-1 ? DGRID-1 : c2);
    int v = ((batch[i]*DGRID + c0)*DGRID + c1)*DGRID + c2;
    vox[i] = v;
    atomicAdd(&h[v], 1);
  }
  __syncthreads();
  for (int t = threadIdx.x; t < NVOX; t += 256)
    chunkHist[c * NVOX + t] = h[t];
}

// F3: per-group partial sums over chunks (coalesced along v)
__global__ __launch_bounds__(256) void k_gsum(int nchunks, int ngroups,
    const int* __restrict__ chunkHist, int* __restrict__ gsum){
  int g = blockIdx.x >> 3;
  int v = (blockIdx.x & 7) * 256 + threadIdx.x;
  if (g >= ngroups) return;
  int c0 = g * GRP, c1 = min(nchunks, c0 + GRP);
  int s = 0;
  for (int c = c0; c < c1; c++) s += chunkHist[c * NVOX + v];
  gsum[g * NVOX + v] = s;
}

// F4: exclusive scan over groups per voxel -> counts
__global__ __launch_bounds__(256) void k_gscan(int ngroups,
    int* __restrict__ gsum, int* __restrict__ counts){
  int v = blockIdx.x * 256 + threadIdx.x;
  if (v >= NVOX) return;
  int run = 0;
  for (int g = 0; g < ngroups; g++){
    int t = gsum[g * NVOX + v];
    gsum[g * NVOX + v] = run;
    run += t;
  }
  counts[v] = run;
}

// F5: stable scatter + FUSED compaction scan (wave 0 redundant per block;
//     block 0 writes Mout/batchStartC/idxOfCluster/voxBase globals).
//     4 waves = 4 rows; in-row shfl rank + rowCnt prefix. No atomics.
__global__ __launch_bounds__(256) void k_scatter(const float* __restrict__ pos,
    const int* __restrict__ vox, int N, const int* __restrict__ chunkHist,
    const int* __restrict__ gsum, const int* __restrict__ counts,
    int* Mout, int* batchStartC, int* __restrict__ idxOfCluster,
    int* __restrict__ voxBaseG, float* __restrict__ pos_sorted){
  __shared__ int sBase[NVOX];         // 8 KB: voxBase, then chunk base
  __shared__ int rowCnt[4][NVOX];     // 32 KB
  int c = blockIdx.x;
  int wv = threadIdx.x >> 6, lane = threadIdx.x & 63;
  if (wv == 0){
    // redundant single-wave compaction/base scan from counts
    int cs[32];
    int ne = 0, tot = 0;
    #pragma unroll
    for (int j = 0; j < 32; j++){
      int cc2 = counts[lane*32 + j];
      cs[j] = cc2; ne += (cc2 > 0) ? 1 : 0; tot += cc2;
    }
    int inc = ne, incT = tot;
    #pragma unroll
    for (int off = 1; off < 64; off <<= 1){
      int t  = __shfl_up(inc,  off);
      int tt = __shfl_up(incT, off);
      if (lane >= off){ inc += t; incT += tt; }
    }
    int exne = inc - ne, exT = incT - tot;
    int run = exne, bb = exT;
    #pragma unroll
    for (int j = 0; j < 32; j++){
      sBase[lane*32 + j] = bb;
      if (c == 0) voxBaseG[lane*32 + j] = bb;
      bb += cs[j];
      if (cs[j] > 0){
        if (c == 0 && run < MMAX) idxOfCluster[run] = lane*32 + j;
        run++;
      }
    }
    if (c == 0){
      int M = __shfl(run, 63);
      for (int m = M + lane; m < MMAX; m += 64) idxOfCluster[m] = 0;
      int ex0  = __shfl(exne, 0),  ex16 = __shfl(exne, 16);
      int ex32 = __shfl(exne, 32), ex48 = __shfl(exne, 48);
      if (lane == 0){
        Mout[0] = M;
        batchStartC[0] = ex0;  batchStartC[1] = ex16;
        batchStartC[2] = ex32; batchStartC[3] = ex48;
        batchStartC[NBATCH] = (M < MMAX) ? M : MMAX;
      }
    }
  } else {
    for (int t = threadIdx.x - 64; t < 4*NVOX; t += 192)
      ((int*)rowCnt)[t] = 0;
  }
  __syncthreads();
  {
    int g = c / GRP, cg0 = g * GRP;
    for (int t = threadIdx.x; t < NVOX; t += 256){
      int b = sBase[t] + gsum[g * NVOX + t];
      for (int cc = cg0; cc < c; cc++) b += chunkHist[cc * NVOX + t];
      sBase[t] = b;
    }
  }
  __syncthreads();
  int i = c * CHUNKP + threadIdx.x;
  bool valid = i < N;
  int v = valid ? vox[i] : -1;
  float px = 0.f, py = 0.f, pz = 0.f;
  if (valid){ px = pos[3*i+0]; py = pos[3*i+1]; pz = pos[3*i+2]; }
  int rank = 0, cnt = 0;
  #pragma unroll 8
  for (int j = 0; j < 64; j++){
    int vj = __shfl(v, j);
    if (vj == v){
      cnt++;
      if (j < lane) rank++;
    }
  }
  if (valid && rank == 0) rowCnt[wv][v] = cnt;
  __syncthreads();
  if (valid){
    int pre = 0;
    for (int rr = 0; rr < wv; rr++) pre += rowCnt[rr][v];
    int dst = sBase[v] + pre + rank;
    pos_sorted[3*dst+0] = px;
    pos_sorted[3*dst+1] = py;
    pos_sorted[3*dst+2] = pz;
  }
}

// F6: per-voxel fp32 sums (bitwise-sequential __fadd_rn chain) + centroid + c2
__global__ __launch_bounds__(64) void k_sum2cent(const float* __restrict__ pos_sorted,
    const int* __restrict__ voxBase, const int* __restrict__ counts,
    float4* __restrict__ centv){
  int v = blockIdx.x * 64 + threadIdx.x;
  if (v >= NVOX) return;
  int lo = voxBase[v], cnt = counts[v];
  const float* p = pos_sorted + 3*(size_t)lo;
  float sx = 0.f, sy = 0.f, sz = 0.f;
  int k = 0;
  for (; k + 4 <= cnt; k += 4){
    float a0 = p[0],  a1 = p[1],  a2 = p[2];
    float b0 = p[3],  b1 = p[4],  b2 = p[5];
    float c0 = p[6],  c1 = p[7],  c2 = p[8];
    float d0 = p[9],  d1 = p[10], d2 = p[11];
    sx = __fadd_rn(__fadd_rn(__fadd_rn(__fadd_rn(sx, a0), b0), c0), d0);
    sy = __fadd_rn(__fadd_rn(__fadd_rn(__fadd_rn(sy, a1), b1), c1), d1);
    sz = __fadd_rn(__fadd_rn(__fadd_rn(__fadd_rn(sz, a2), b2), c2), d2);
    p += 12;
  }
  for (; k < cnt; k++){
    sx = __fadd_rn(sx, p[0]);
    sy = __fadd_rn(sy, p[1]);
    sz = __fadd_rn(sz, p[2]);
    p += 3;
  }
  float den = fmaxf((float)cnt, 1.0f);
  float cx = __fdiv_rn(sx, den);
  float cy = __fdiv_rn(sy, den);
  float cz = __fdiv_rn(sz, den);
  float c2 = __fadd_rn(__fadd_rn(__fmul_rn(cx,cx), __fmul_rn(cy,cy)), __fmul_rn(cz,cz));
  centv[v] = make_float4(cx, cy, cz, c2);
}

// F7: per-point argmin (EXACT fp32 code) with gathered centroid table;
//     block 0 writes outC/outNB/outValid; fused LDS cluster hist -> clustCnt.
__global__ __launch_bounds__(256) void k_argmin2(const float* __restrict__ pos,
    const int* __restrict__ batch, int N, const float4* __restrict__ centv,
    const int* __restrict__ idxOfCluster, const int* __restrict__ Mout,
    const int* __restrict__ batchStartC, int* __restrict__ assign,
    int* __restrict__ clustCnt, float* __restrict__ outC,
    float* __restrict__ outNB, float* __restrict__ outValid){
  __shared__ float4 sc[MMAX];         // 16 KB
  __shared__ int h[MMAX];             // 4 KB
  for (int m = threadIdx.x; m < MMAX; m += 256){
    sc[m] = centv[idxOfCluster[m]];
    h[m] = 0;
  }
  __syncthreads();
  if (blockIdx.x == 0){
    int M = Mout[0];
    for (int m = threadIdx.x; m < MMAX; m += 256){
      float4 cc = sc[m];
      outC[3*m+0] = cc.x; outC[3*m+1] = cc.y; outC[3*m+2] = cc.z;
      outNB[m] = (float)(idxOfCluster[m] >> 9);
      outValid[m] = (m < M) ? 1.0f : 0.0f;
    }
  }
  int i = blockIdx.x * 256 + threadIdx.x;
  if (i < N){
    float px = pos[3*i+0], py = pos[3*i+1], pz = pos[3*i+2];
    float p2 = __fadd_rn(__fadd_rn(__fmul_rn(px,px), __fmul_rn(py,py)), __fmul_rn(pz,pz));
    int b = batch[i];
    int mlo = batchStartC[b], mhi = batchStartC[b+1];
    float best = 3.402823466e+38f;
    int bm = mlo;
    for (int m = mlo; m < mhi; m++){
      float4 cc = sc[m];
      float dot = __fadd_rn(__fadd_rn(__fmul_rn(px,cc.x), __fmul_rn(py,cc.y)),
                            __fmul_rn(pz,cc.z));
      float d2  = __fadd_rn(__fsub_rn(p2, __fmul_rn(2.0f, dot)), cc.w);
      if (d2 < best){ best = d2; bm = m; }
    }
    assign[i] = bm;
    atomicAdd(&h[bm], 1);
  }
  __syncthreads();
  for (int t = threadIdx.x; t < MMAX; t += 256){
    int c = h[t];
    if (c > 0) atomicAdd(&clustCnt[t], c);
  }
}

// F8: index scatter by cluster + FUSED redundant cluster-base scan (wave 0;
//     block 0 writes clustBaseG). Rank via global clustRank atomics
//     (zeroed in k_minpart). fmax is order-independent -> unordered ok.
__global__ __launch_bounds__(256) void k_scatter2s(const int* __restrict__ assign,
    int N, const int* __restrict__ clustCnt, int* __restrict__ clustRank,
    int* __restrict__ clustBaseG, int* __restrict__ idx_sorted){
  __shared__ int cb[MMAX];            // 4 KB
  int wv = threadIdx.x >> 6, lane = threadIdx.x & 63;
  if (wv == 0){
    int cs[16]; int tot = 0;
    #pragma unroll
    for (int j = 0; j < 16; j++){ cs[j] = clustCnt[lane*16 + j]; tot += cs[j]; }
    int inc = tot;
    #pragma unroll
    for (int off = 1; off < 64; off <<= 1){
      int t = __shfl_up(inc, off);
      if (lane >= off) inc += t;
    }
    int bb = inc - tot;
    #pragma unroll
    for (int j = 0; j < 16; j++){
      cb[lane*16 + j] = bb;
      if (blockIdx.x == 0) clustBaseG[lane*16 + j] = bb;
      bb += cs[j];
    }
  }
  __syncthreads();
  int i = blockIdx.x * 256 + threadIdx.x;
  if (i >= N) return;
  int m = assign[i];
  int r = atomicAdd(&clustRank[m], 1);
  idx_sorted[cb[m] + r] = i;
}

// F9: per-cluster feature max. One wave per cluster, lane = feature.
__global__ __launch_bounds__(256) void k_xmax(const float* __restrict__ x,
    const int* __restrict__ idx_sorted, const int* __restrict__ clustBase,
    const int* __restrict__ clustCnt, float* __restrict__ outX){
  int w = blockIdx.x * 4 + (threadIdx.x >> 6);
  int lane = threadIdx.x & 63;
  if (w >= MMAX) return;
  int lo = clustBase[w], cnt = clustCnt[w];
  float mx = -3.402823466e+38f;
  int k = 0;
  for (; k + 4 <= cnt; k += 4){
    int r0 = idx_sorted[lo+k+0], r1 = idx_sorted[lo+k+1];
    int r2 = idx_sorted[lo+k+2], r3 = idx_sorted[lo+k+3];
    float a = x[(size_t)r0 * FDIM + lane];
    float b = x[(size_t)r1 * FDIM + lane];
    float c = x[(size_t)r2 * FDIM + lane];
    float d = x[(size_t)r3 * FDIM + lane];
    mx = fmaxf(mx, fmaxf(fmaxf(a, b), fmaxf(c, d)));
  }
  for (; k < cnt; k++){
    int r0 = idx_sorted[lo+k];
    mx = fmaxf(mx, x[(size_t)r0 * FDIM + lane]);
  }
  outX[w * FDIM + lane] = (cnt > 0) ? mx : 0.0f;
}

// ======================= SLOW-PATH FALLBACK (ws too small) =======================

__global__ __launch_bounds__(256) void k_init(unsigned* startEnc, int* batchCnt){
  int t = threadIdx.x;
  if (t < 3) startEnc[t] = 0xFFFFFFFFu;
  if (t < NBATCH) batchCnt[t] = 0;
}

__global__ __launch_bounds__(256) void k_min_hist(const float* __restrict__ pos,
    const int* __restrict__ batch, int N, unsigned* startEnc, int* batchCnt){
  __shared__ int sbin[NBATCH];
  if (threadIdx.x < NBATCH) sbin[threadIdx.x] = 0;
  __syncthreads();
  unsigned m0 = 0xFFFFFFFFu, m1 = 0xFFFFFFFFu, m2 = 0xFFFFFFFFu;
  int stride = gridDim.x * blockDim.x;
  for (int i = blockIdx.x * blockDim.x + threadIdx.x; i < N; i += stride){
    unsigned e0 = encf(pos[3*i+0]); if (e0 < m0) m0 = e0;
    unsigned e1 = encf(pos[3*i+1]); if (e1 < m1) m1 = e1;
    unsigned e2 = encf(pos[3*i+2]); if (e2 < m2) m2 = e2;
    atomicAdd(&sbin[batch[i]], 1);
  }
  #pragma unroll
  for (int off = 32; off > 0; off >>= 1){
    unsigned t0 = __shfl_down(m0, off); if (t0 < m0) m0 = t0;
    unsigned t1 = __shfl_down(m1, off); if (t1 < m1) m1 = t1;
    unsigned t2 = __shfl_down(m2, off); if (t2 < m2) m2 = t2;
  }
  if ((threadIdx.x & 63) == 0){
    atomicMin(&startEnc[0], m0);
    atomicMin(&startEnc[1], m1);
    atomicMin(&startEnc[2], m2);
  }
  __syncthreads();
  if (threadIdx.x < NBATCH) atomicAdd(&batchCnt[threadIdx.x], sbin[threadIdx.x]);
}

__global__ __launch_bounds__(256) void k_vox(const float* __restrict__ pos,
    const int* __restrict__ batch, int N, const unsigned* __restrict__ startEnc,
    int* __restrict__ vox, int* __restrict__ counts){
  int i = blockIdx.x * blockDim.x + threadIdx.x;
  if (i >= N) return;
  float s0 = __fsub_rn(decf(startEnc[0]), 0.1f);
  float s1 = __fsub_rn(decf(startEnc[1]), 0.1f);
  float s2 = __fsub_rn(decf(startEnc[2]), 0.1f);
  float q0 = __fdiv_rn(__fsub_rn(pos[3*i+0], s0), 0.2f);
  float q1 = __fdiv_rn(__fsub_rn(pos[3*i+1], s1), 0.2f);
  float q2 = __fdiv_rn(__fsub_rn(pos[3*i+2], s2), 0.2f);
  int c0 = (int)floorf(q0); c0 = c0 < 0 ? 0 : (c0 > DGRID-1 ? DGRID-1 : c0);
  int c1 = (int)floorf(q1); c1 = c1 < 0 ? 0 : (c1 > DGRID-1 ? DGRID-1 : c1);
  int c2 = (int)floorf(q2); c2 = c2 < 0 ? 0 : (c2 > DGRID-1 ? DGRID-1 : c2);
  int v = ((batch[i]*DGRID + c0)*DGRID + c1)*DGRID + c2;
  vox[i] = v;
  atomicAdd(&counts[v], 1);
}

__global__ __launch_bounds__(64) void k_scan_old(const int* __restrict__ counts,
    const int* __restrict__ batchCnt, int* batchPtr, int* Mout,
    int* batchStartC, int* __restrict__ idxOfCluster, int* __restrict__ voxBase){
  int lane = threadIdx.x;
  int cs[32];
  int ne = 0, tot = 0;
  #pragma unroll
  for (int j = 0; j < 32; j++){
    int c = counts[lane*32 + j];
    cs[j] = c;
    ne += (c > 0) ? 1 : 0;
    tot += c;
  }
  int inc = ne, incT = tot;
  #pragma unroll
  for (int off = 1; off < 64; off <<= 1){
    int t  = __shfl_up(inc,  off);
    int tt = __shfl_up(incT, off);
    if (lane >= off){ inc += t; incT += tt; }
  }
  int exne = inc - ne;
  int bb   = incT - tot;
  int run = exne;
  #pragma unroll
  for (int j = 0; j < 32; j++){
    voxBase[lane*32 + j] = bb;
    bb += cs[j];
    if (cs[j] > 0){
      if (run < MMAX) idxOfCluster[run] = lane*32 + j;
      run++;
    }
  }
  int M = __shfl(run, 63);
  for (int m = M + lane; m < MMAX; m += 64) idxOfCluster[m] = 0;
  int ex0  = __shfl(exne, 0);
  int ex16 = __shfl(exne, 16);
  int ex32 = __shfl(exne, 32);
  int ex48 = __shfl(exne, 48);
  if (lane == 0){
    Mout[0] = M;
    int acc = 0;
    for (int b = 0; b < NBATCH; b++){ batchPtr[b] = acc; acc += batchCnt[b]; }
    batchPtr[NBATCH] = acc;
    batchStartC[0] = ex0;  batchStartC[1] = ex16;
    batchStartC[2] = ex32; batchStartC[3] = ex48;
    batchStartC[NBATCH] = (M < MMAX) ? M : MMAX;
  }
}

__global__ __launch_bounds__(64) void k_sum(const float* __restrict__ pos,
    const int* __restrict__ vox, const int* __restrict__ counts,
    const int* __restrict__ batchPtr, float* __restrict__ sum_pos){
  int v = blockIdx.x * 64 + threadIdx.x;
  if (v >= NVOX) return;
  int b = v >> 9;
  int lo = batchPtr[b], hi = batchPtr[b+1];
  float sx = 0.f, sy = 0.f, sz = 0.f;
  if (counts[v] > 0){
    for (int i = lo; i < hi; i++){
      if (vox[i] == v){
        sx = __fadd_rn(sx, pos[3*i+0]);
        sy = __fadd_rn(sy, pos[3*i+1]);
        sz = __fadd_rn(sz, pos[3*i+2]);
      }
    }
  }
  sum_pos[3*v+0] = sx;
  sum_pos[3*v+1] = sy;
  sum_pos[3*v+2] = sz;
}

__global__ __launch_bounds__(256) void k_cent(const float* __restrict__ sum_pos,
    const int* __restrict__ counts, const int* __restrict__ idxOfCluster,
    const int* __restrict__ Mout, float4* __restrict__ cent4,
    float* __restrict__ outC, float* __restrict__ outNB, float* __restrict__ outValid){
  int m = blockIdx.x * blockDim.x + threadIdx.x;
  if (m >= MMAX) return;
  int M = Mout[0];
  int v = idxOfCluster[m];
  float den = fmaxf((float)counts[v], 1.0f);
  float cx = __fdiv_rn(sum_pos[3*v+0], den);
  float cy = __fdiv_rn(sum_pos[3*v+1], den);
  float cz = __fdiv_rn(sum_pos[3*v+2], den);
  float c2 = __fadd_rn(__fadd_rn(__fmul_rn(cx,cx), __fmul_rn(cy,cy)), __fmul_rn(cz,cz));
  cent4[m] = make_float4(cx, cy, cz, c2);
  outC[3*m+0] = cx; outC[3*m+1] = cy; outC[3*m+2] = cz;
  outNB[m] = (float)(v >> 9);
  outValid[m] = (m < M) ? 1.0f : 0.0f;
}

__global__ __launch_bounds__(256) void k_assign_slow(const float* __restrict__ pos,
    const float* __restrict__ x, const int* __restrict__ batch, int N,
    const float4* __restrict__ cent4, const int* __restrict__ batchStartC,
    unsigned* __restrict__ encMax){
  __shared__ float4 sc[MMAX];
  for (int m = threadIdx.x; m < MMAX; m += blockDim.x) sc[m] = cent4[m];
  __syncthreads();
  int i = blockIdx.x * blockDim.x + threadIdx.x;
  if (i >= N) return;
  float px = pos[3*i+0], py = pos[3*i+1], pz = pos[3*i+2];
  float p2 = __fadd_rn(__fadd_rn(__fmul_rn(px,px), __fmul_rn(py,py)), __fmul_rn(pz,pz));
  int b = batch[i];
  int mlo = batchStartC[b], mhi = batchStartC[b+1];
  float best = 3.402823466e+38f;
  int bm = mlo;
  for (int m = mlo; m < mhi; m++){
    float4 c = sc[m];
    float dot = __fadd_rn(__fadd_rn(__fmul_rn(px,c.x), __fmul_rn(py,c.y)),
                          __fmul_rn(pz,c.z));
    float d2  = __fadd_rn(__fsub_rn(p2, __fmul_rn(2.0f, dot)), c.w);
    if (d2 < best){ best = d2; bm = m; }
  }
  unsigned* dst = encMax + bm * FDIM;
  const float4* xi = (const float4*)(x + (size_t)i * FDIM);
  #pragma unroll
  for (int f4 = 0; f4 < FDIM/4; f4++){
    float4 xv = xi[f4];
    atomicMax(&dst[4*f4+0], encf(xv.x));
    atomicMax(&dst[4*f4+1], encf(xv.y));
    atomicMax(&dst[4*f4+2], encf(xv.z));
    atomicMax(&dst[4*f4+3], encf(xv.w));
  }
}
__global__ __launch_bounds__(256) void k_decode(const unsigned* __restrict__ encMax,
    float* __restrict__ outX){
  int t = blockIdx.x * blockDim.x + threadIdx.x;
  if (t >= MMAX * FDIM) return;
  unsigned e = encMax[t];
  outX[t] = (e == 0u) ? 0.0f : decf(e);
}

// ---- workspace layout (bytes) ----
// 0      : bmin          64 x 3 x u32 (768)
// 768    : startEnc      12   (slow)
// 784    : batchCnt      16   (slow)
// 800    : batchPtr      20   (slow)
// 832    : Mout          4
// 848    : batchStartC   20
// 896    : counts        8192
// 9088   : voxBase(G)    8192
// 17280  : sum_pos       24576 (slow)
// 41856  : idxOfCluster  4096
// 45952  : cent4         16384 (slow)
// 62336  : clustCnt      4096
// 66432  : clustBase(G)  4096
// 70528  : clustRank     4096  (slow: "cur")
// 74624  : centv         2048 x float4 (32768)
// 107392 : encMax 256KB (slow) / gsum ngroups x 2048 x i32 (fast, <=256KB)
// 369536 : vox           N x i32
// then   : chunkHist     nchunks x 2048 x i32
// then   : pos_sorted    N x 3 x f32  [alias after k_sum2cent: assign(N) | idx_sorted(N)]

extern "C" void kernel_launch(void* const* d_in, const int* in_sizes, int n_in,
                              void* d_out, int out_size, void* d_ws, size_t ws_size,
                              hipStream_t stream){
  const float* pos   = (const float*)d_in[0];
  const float* x     = (const float*)d_in[1];
  const int*   batch = (const int*)d_in[2];
  const int N = in_sizes[2];

  char* w = (char*)d_ws;
  unsigned* bmin         = (unsigned*)(w + 0);
  unsigned* startEnc     = (unsigned*)(w + 768);
  int*      batchCnt     = (int*)(w + 784);
  int*      batchPtr     = (int*)(w + 800);
  int*      Mout         = (int*)(w + 832);
  int*      batchStartC  = (int*)(w + 848);
  int*      counts       = (int*)(w + 896);
  int*      voxBaseG     = (int*)(w + 9088);
  float*    sum_pos      = (float*)(w + 17280);
  int*      idxOfCluster = (int*)(w + 41856);
  float4*   cent4        = (float4*)(w + 45952);
  int*      clustCnt     = (int*)(w + 62336);
  int*      clustBaseG   = (int*)(w + 66432);
  int*      clustRank    = (int*)(w + 70528);
  float4*   centv        = (float4*)(w + 74624);
  unsigned* encMax       = (unsigned*)(w + 107392);
  int*      gsum         = (int*)(w + 107392);   // fast-path alias
  int*      vox          = (int*)(w + 369536);
  size_t voxEnd = 369536 + (size_t)N * 4;
  size_t chOff  = (voxEnd + 15) & ~(size_t)15;

  int nchunks = (N + CHUNKP - 1) / CHUNKP;
  int ngroups = (nchunks + GRP - 1) / GRP;
  size_t psOff = chOff + (size_t)nchunks * NVOX * 4;
  size_t need  = psOff + (size_t)N * 3 * 4;
  const bool fast = (ws_size >= need) && (ngroups <= 32);

  int*   chunkHist  = (int*)(w + chOff);
  float* pos_sorted = (float*)(w + psOff);
  int* assign     = (int*)pos_sorted;         // after k_sum2cent
  int* idx_sorted = (int*)pos_sorted + N;

  float* outX     = (float*)d_out;          // [1024,64]
  float* outC     = outX + MMAX * FDIM;     // [1024,3]
  float* outNB    = outC + MMAX * 3;        // [1024]
  float* outValid = outNB + MMAX;           // [1024]

  const int nb = (N + 255) / 256;
  if (fast){
    k_minpart<<<64, 256, 0, stream>>>(pos, N, bmin, counts, clustCnt, clustRank);
    k_vox_hist<<<nchunks, 256, 0, stream>>>(pos, batch, N, bmin, vox, chunkHist);
    k_gsum<<<ngroups * 8, 256, 0, stream>>>(nchunks, ngroups, chunkHist, gsum);
    k_gscan<<<NVOX / 256, 256, 0, stream>>>(ngroups, gsum, counts);
    k_scatter<<<nchunks, 256, 0, stream>>>(pos, vox, N, chunkHist, gsum, counts,
                                           Mout, batchStartC, idxOfCluster,
                                           voxBaseG, pos_sorted);
    k_sum2cent<<<NVOX / 64, 64, 0, stream>>>(pos_sorted, voxBaseG, counts, centv);
    k_argmin2<<<nb, 256, 0, stream>>>(pos, batch, N, centv, idxOfCluster, Mout,
                                      batchStartC, assign, clustCnt,
                                      outC, outNB, outValid);
    k_scatter2s<<<nb, 256, 0, stream>>>(assign, N, clustCnt, clustRank,
                                        clustBaseG, idx_sorted);
    k_xmax<<<MMAX / 4, 256, 0, stream>>>(x, idx_sorted, clustBaseG, clustCnt, outX);
  } else {
    k_init<<<1, 256, 0, stream>>>(startEnc, batchCnt);
    hipMemsetAsync(counts, 0, NVOX * 4, stream);
    hipMemsetAsync(encMax, 0, MMAX * FDIM * 4, stream);
    k_min_hist<<<256, 256, 0, stream>>>(pos, batch, N, startEnc, batchCnt);
    k_vox<<<nb, 256, 0, stream>>>(pos, batch, N, startEnc, vox, counts);
    k_scan_old<<<1, 64, 0, stream>>>(counts, batchCnt, batchPtr, Mout, batchStartC,
                                     idxOfCluster, voxBaseG);
    k_sum<<<(NVOX + 63) / 64, 64, 0, stream>>>(pos, vox, counts, batchPtr, sum_pos);
    k_cent<<<MMAX / 256, 256, 0, stream>>>(sum_pos, counts, idxOfCluster, Mout,
                                           cent4, outC, outNB, outValid);
    k_assign_slow<<<nb, 256, 0, stream>>>(pos, x, batch, N, cent4, batchStartC, encMax);
    k_decode<<<(MMAX * FDIM + 255) / 256, 256, 0, stream>>>(encMax, outX);
  }
}